// Round 2
// baseline (1557.869 us; speedup 1.0000x reference)
//
#include <hip/hip_runtime.h>
#include <math.h>

#define TDIM 4096
#define DDIM 1024
#define HDIM 256
#define BB   4

#define AQ 32     // queries per block
#define AK 128    // keys per iteration

// ---------------- Kernel 1: fused QKV projection ----------------
// C_w = A[16384 x 1024] * W_w[1024 x 256],  w in {q,k,v} selected by blockIdx.y>>2
__global__ __launch_bounds__(256) void qkv_gemm(
    const float* __restrict__ A,
    const float* __restrict__ Wq, const float* __restrict__ Wk, const float* __restrict__ Wv,
    float* __restrict__ Qo, float* __restrict__ Ko, float* __restrict__ Vo)
{
  __shared__ float sAt[16][68];   // A chunk transposed [k][m]
  __shared__ float sB[16][68];    // W chunk [k][n]
  const int tid = threadIdx.x;
  const int tx = tid & 15, ty = tid >> 4;
  const int m0 = blockIdx.x * 64;
  const int nt = blockIdx.y;            // 0..11
  const int w  = nt >> 2;
  const int n0 = (nt & 3) * 64;
  const float* W = (w == 0) ? Wq : (w == 1) ? Wk : Wv;
  float*       C = (w == 0) ? Qo : (w == 1) ? Ko : Vo;

  const int ar = tid >> 2, ac = (tid & 3) * 4;     // A stage: 64 rows x 16 k
  const int br = tid >> 4, bc = (tid & 15) * 4;    // B stage: 16 k x 64 n

  float acc[4][4] = {};
  for (int k0 = 0; k0 < DDIM; k0 += 16) {
    float4 av = *reinterpret_cast<const float4*>(&A[(size_t)(m0 + ar) * DDIM + k0 + ac]);
    float4 bv = *reinterpret_cast<const float4*>(&W[(size_t)(k0 + br) * HDIM + n0 + bc]);
    __syncthreads();
    sAt[ac + 0][ar] = av.x; sAt[ac + 1][ar] = av.y;
    sAt[ac + 2][ar] = av.z; sAt[ac + 3][ar] = av.w;
    *reinterpret_cast<float4*>(&sB[br][bc]) = bv;
    __syncthreads();
#pragma unroll
    for (int kk = 0; kk < 16; ++kk) {
      float4 a4 = *reinterpret_cast<const float4*>(&sAt[kk][4 * ty]);
      float4 b4 = *reinterpret_cast<const float4*>(&sB[kk][4 * tx]);
      float a_[4] = {a4.x, a4.y, a4.z, a4.w};
      float b_[4] = {b4.x, b4.y, b4.z, b4.w};
#pragma unroll
      for (int i = 0; i < 4; ++i)
#pragma unroll
        for (int j = 0; j < 4; ++j)
          acc[i][j] = fmaf(a_[i], b_[j], acc[i][j]);
    }
  }
#pragma unroll
  for (int i = 0; i < 4; ++i) {
    float4 o4 = {acc[i][0], acc[i][1], acc[i][2], acc[i][3]};
    *reinterpret_cast<float4*>(&C[(size_t)(m0 + 4 * ty + i) * HDIM + n0 + 4 * tx]) = o4;
  }
}

// ---------------- Kernel 2: fp32 flash attention ----------------
// One block: 32 query rows of one batch. Iterates 128-key blocks with online softmax.
// Thread map: txs = tid&31 (S cols / O cols), tys = tid>>5 (rows, 4 per thread).
__global__ __launch_bounds__(256) void attn_fp32(
    const float* __restrict__ Q, const float* __restrict__ K, const float* __restrict__ V,
    float* __restrict__ O)
{
  __shared__ float sQt[64][36];      // Q chunk transposed [h][row], pre-scaled by 0.5
  __shared__ float sKV[8448];        // union: Kt chunk [64][132]  |  V chunk [32][260]
  __shared__ float sPt[128][36];     // P transposed [key][row]

  const int tid = threadIdx.x;
  const int txs = tid & 31, tys = tid >> 5;
  const int b  = blockIdx.y;
  const int q0 = blockIdx.x * AQ;
  const size_t base = (size_t)b * TDIM * HDIM;

  float o[4][2][4] = {};
  float m[4], l[4];
#pragma unroll
  for (int i = 0; i < 4; ++i) { m[i] = -INFINITY; l[i] = 0.f; }

  for (int kb = 0; kb < TDIM / AK; ++kb) {
    float s[4][4] = {};
    // ---- S = (Q*0.5) @ K^T over 4 h-chunks of 64 ----
    for (int hc = 0; hc < 4; ++hc) {
      __syncthreads();
      {   // stage Q chunk transposed: 32 rows x 64 h  (2 float4 per thread)
        int f = tid;
#pragma unroll
        for (int i = 0; i < 2; ++i, f += 256) {
          int row = f >> 4, c4 = (f & 15) * 4;
          float4 v = *reinterpret_cast<const float4*>(
              &Q[base + (size_t)(q0 + row) * HDIM + hc * 64 + c4]);
          sQt[c4 + 0][row] = v.x * 0.5f;
          sQt[c4 + 1][row] = v.y * 0.5f;
          sQt[c4 + 2][row] = v.z * 0.5f;
          sQt[c4 + 3][row] = v.w * 0.5f;
        }
      }
      {   // stage K chunk transposed: 128 keys x 64 h (8 float4 per thread)
        int f = tid;
#pragma unroll
        for (int i = 0; i < 8; ++i, f += 256) {
          int key = f >> 4, c4 = (f & 15) * 4;
          float4 v = *reinterpret_cast<const float4*>(
              &K[base + (size_t)(kb * AK + key) * HDIM + hc * 64 + c4]);
          float* kt = &sKV[(size_t)c4 * 132 + key];
          kt[0] = v.x; kt[132] = v.y; kt[264] = v.z; kt[396] = v.w;
        }
      }
      __syncthreads();
#pragma unroll 8
      for (int h = 0; h < 64; ++h) {
        float4 qa = *reinterpret_cast<const float4*>(&sQt[h][4 * tys]);
        float4 kk = *reinterpret_cast<const float4*>(&sKV[(size_t)h * 132 + 4 * txs]);
        float qa_[4] = {qa.x, qa.y, qa.z, qa.w};
        float kk_[4] = {kk.x, kk.y, kk.z, kk.w};
#pragma unroll
        for (int i = 0; i < 4; ++i)
#pragma unroll
          for (int c = 0; c < 4; ++c)
            s[i][c] = fmaf(qa_[i], kk_[c], s[i][c]);
      }
    }
    // ---- online softmax (rows live on 32-lane groups) ----
    float a_[4];
#pragma unroll
    for (int i = 0; i < 4; ++i) {
      float v = fmaxf(fmaxf(s[i][0], s[i][1]), fmaxf(s[i][2], s[i][3]));
#pragma unroll
      for (int off = 1; off < 32; off <<= 1)
        v = fmaxf(v, __shfl_xor(v, off, 64));
      float mn = fmaxf(m[i], v);
      a_[i] = __expf(m[i] - mn);
      m[i] = mn;
      float su = 0.f;
#pragma unroll
      for (int c = 0; c < 4; ++c) { s[i][c] = __expf(s[i][c] - mn); su += s[i][c]; }
#pragma unroll
      for (int off = 1; off < 32; off <<= 1)
        su += __shfl_xor(su, off, 64);
      l[i] = l[i] * a_[i] + su;
#pragma unroll
      for (int cc = 0; cc < 2; ++cc)
#pragma unroll
        for (int j = 0; j < 4; ++j) o[i][cc][j] *= a_[i];
    }
    // ---- write P^T to LDS ----
#pragma unroll
    for (int c = 0; c < 4; ++c) {
      float4 pc = {s[0][c], s[1][c], s[2][c], s[3][c]};
      *reinterpret_cast<float4*>(&sPt[4 * txs + c][4 * tys]) = pc;
    }
    // ---- O += P @ V over 4 key-chunks of 32 (full-width V rows) ----
    for (int kc = 0; kc < 4; ++kc) {
      __syncthreads();
      {   // stage V chunk: 32 keys x 256 h (8 float4 per thread)
        int f = tid;
#pragma unroll
        for (int i = 0; i < 8; ++i, f += 256) {
          int key = f >> 6, c4 = (f & 63) * 4;
          float4 v = *reinterpret_cast<const float4*>(
              &V[base + (size_t)(kb * AK + kc * 32 + key) * HDIM + c4]);
          *reinterpret_cast<float4*>(&sKV[(size_t)key * 260 + c4]) = v;
        }
      }
      __syncthreads();
#pragma unroll 4
      for (int k = 0; k < 32; ++k) {
        float4 pr = *reinterpret_cast<const float4*>(&sPt[kc * 32 + k][4 * tys]);
        float4 va = *reinterpret_cast<const float4*>(&sKV[(size_t)k * 260 + 4 * txs]);
        float4 vb = *reinterpret_cast<const float4*>(&sKV[(size_t)k * 260 + 4 * txs + 128]);
        float pr_[4] = {pr.x, pr.y, pr.z, pr.w};
        float va_[4] = {va.x, va.y, va.z, va.w};
        float vb_[4] = {vb.x, vb.y, vb.z, vb.w};
#pragma unroll
        for (int i = 0; i < 4; ++i) {
#pragma unroll
          for (int j = 0; j < 4; ++j) {
            o[i][0][j] = fmaf(pr_[i], va_[j], o[i][0][j]);
            o[i][1][j] = fmaf(pr_[i], vb_[j], o[i][1][j]);
          }
        }
      }
    }
  }
  // ---- epilogue: normalize and store ----
#pragma unroll
  for (int i = 0; i < 4; ++i) {
    float inv = 1.0f / l[i];
#pragma unroll
    for (int cc = 0; cc < 2; ++cc) {
      float4 o4 = {o[i][cc][0] * inv, o[i][cc][1] * inv,
                   o[i][cc][2] * inv, o[i][cc][3] * inv};
      *reinterpret_cast<float4*>(
          &O[base + (size_t)(q0 + 4 * tys + i) * HDIM + 4 * txs + 128 * cc]) = o4;
    }
  }
}

extern "C" void kernel_launch(void* const* d_in, const int* in_sizes, int n_in,
                              void* d_out, int out_size, void* d_ws, size_t ws_size,
                              hipStream_t stream) {
  const float* inp = (const float*)d_in[0];
  const float* Wq  = (const float*)d_in[1];
  const float* Wk  = (const float*)d_in[2];
  const float* Wv  = (const float*)d_in[3];
  float* out = (float*)d_out;

  // workspace: Q, K, V each [B*T][H] fp32 = 16 MB  (needs 48 MB total)
  float* Qb = (float*)d_ws;
  float* Kb = Qb + (size_t)BB * TDIM * HDIM;
  float* Vb = Kb + (size_t)BB * TDIM * HDIM;

  qkv_gemm<<<dim3(16384 / 64, 12), 256, 0, stream>>>(inp, Wq, Wk, Wv, Qb, Kb, Vb);
  attn_fp32<<<dim3(TDIM / AQ, BB), 256, 0, stream>>>(Qb, Kb, Vb, out);
}

// Round 6
// 955.481 us; speedup vs baseline: 1.6305x; 1.6305x over previous
//
#include <hip/hip_runtime.h>
#include <hip/hip_fp16.h>
#include <math.h>

#define TDIM 4096
#define DDIM 1024
#define HDIM 256
#define BB   4

typedef _Float16 f16;
typedef f16  half8  __attribute__((ext_vector_type(8)));
typedef float floatx4 __attribute__((ext_vector_type(4)));

union U4 { uint4 u; half8 h; };

#define KPITCH 264   // f16 elems per K_lds row (256 + 8 pad; 528 B, 16B-aligned)
#define VPITCH 40    // f16 elems per V^T_lds row (32 + 8 pad; 80 B, 16B-aligned)

__device__ inline unsigned pk16(float a, float b) {
  auto r = __builtin_amdgcn_cvt_pkrtz(a, b);   // __fp16 ext_vector_type(2)
  return __builtin_bit_cast(unsigned, r);
}

// ---------------- Kernel 1: fused QKV projection (fp32 math) ----------------
// Outputs: Qs = 0.5*Q fp32 [16384][256]; Khi/Klo f16 [16384][256]; Vt f16 [B][256][4096]
__global__ __launch_bounds__(256) void qkv_gemm(
    const float* __restrict__ A,
    const float* __restrict__ Wq, const float* __restrict__ Wk, const float* __restrict__ Wv,
    float* __restrict__ Qs, f16* __restrict__ Khi, f16* __restrict__ Klo,
    f16* __restrict__ Vt)
{
  __shared__ float sAt[16][68];
  __shared__ float sB[16][68];
  const int tid = threadIdx.x;
  const int tx = tid & 15, ty = tid >> 4;
  const int m0 = blockIdx.x * 64;
  const int nt = blockIdx.y;            // 0..11
  const int w  = nt >> 2;
  const int n0 = (nt & 3) * 64;
  const float* W = (w == 0) ? Wq : (w == 1) ? Wk : Wv;

  const int ar = tid >> 2, ac = (tid & 3) * 4;
  const int br = tid >> 4, bc = (tid & 15) * 4;

  float acc[4][4] = {};
  for (int k0 = 0; k0 < DDIM; k0 += 16) {
    float4 av = *reinterpret_cast<const float4*>(&A[(size_t)(m0 + ar) * DDIM + k0 + ac]);
    float4 bv = *reinterpret_cast<const float4*>(&W[(size_t)(k0 + br) * HDIM + n0 + bc]);
    __syncthreads();
    sAt[ac + 0][ar] = av.x; sAt[ac + 1][ar] = av.y;
    sAt[ac + 2][ar] = av.z; sAt[ac + 3][ar] = av.w;
    *reinterpret_cast<float4*>(&sB[br][bc]) = bv;
    __syncthreads();
#pragma unroll
    for (int kk = 0; kk < 16; ++kk) {
      float4 a4 = *reinterpret_cast<const float4*>(&sAt[kk][4 * ty]);
      float4 b4 = *reinterpret_cast<const float4*>(&sB[kk][4 * tx]);
      float a_[4] = {a4.x, a4.y, a4.z, a4.w};
      float b_[4] = {b4.x, b4.y, b4.z, b4.w};
#pragma unroll
      for (int i = 0; i < 4; ++i)
#pragma unroll
        for (int j = 0; j < 4; ++j)
          acc[i][j] = fmaf(a_[i], b_[j], acc[i][j]);
    }
  }
#pragma unroll
  for (int i = 0; i < 4; ++i) {
    const int mrow = m0 + 4 * ty + i;
    if (w == 0) {
      float4 o4 = {acc[i][0] * 0.5f, acc[i][1] * 0.5f, acc[i][2] * 0.5f, acc[i][3] * 0.5f};
      *reinterpret_cast<float4*>(&Qs[(size_t)mrow * HDIM + n0 + 4 * tx]) = o4;
    } else if (w == 1) {
#pragma unroll
      for (int j = 0; j < 4; ++j) {
        float x = acc[i][j];
        f16 hi = (f16)x;
        Khi[(size_t)mrow * HDIM + n0 + 4 * tx + j] = hi;
        Klo[(size_t)mrow * HDIM + n0 + 4 * tx + j] = (f16)(x - (float)hi);
      }
    } else {
      const int bb = mrow >> 12, t = mrow & 4095;
#pragma unroll
      for (int j = 0; j < 4; ++j)
        Vt[(size_t)bb * HDIM * TDIM + (size_t)(n0 + 4 * tx + j) * TDIM + t] = (f16)acc[i][j];
    }
  }
}

// ---------------- Kernel 2: MFMA flash attention (fp16x3 QK^T, fp16 PV) ----------------
// 4 waves/block, wave owns 16 q rows; KB=32 keys/iter.
// Swapped S^T = mfma(A=K, B=Q): C row=key(4g+r), col=q(lane&15).
__global__ __launch_bounds__(256) void attn_mfma(
    const float* __restrict__ Qs, const f16* __restrict__ Khi,
    const f16* __restrict__ Klo, const f16* __restrict__ Vt,
    float* __restrict__ O)
{
  __shared__ f16 sKhi[32 * KPITCH];
  __shared__ f16 sKlo[32 * KPITCH];
  __shared__ f16 sVt[256 * VPITCH];

  const int tid = threadIdx.x;
  const int lane = tid & 63;
  const int wv = tid >> 6;
  const int ql = lane & 15;
  const int g  = lane >> 4;

  // XCD-affinity swizzle: batch b -> XCDs 2b,2b+1 (bijective over 256 blocks)
  const int i = blockIdx.x;
  const int b = (i & 7) >> 1;
  const int p = ((i >> 3) << 1) | (i & 1);
  const size_t tb = (size_t)b * TDIM;

  const int q0 = p * 64 + wv * 16;

  // ---- hoist Q fragments: split scaled fp32 Q into hi/lo f16 ----
  half8 qhi[8], qlo[8];
  {
    const float* qr = Qs + (tb + q0 + ql) * HDIM;
#pragma unroll
    for (int hc = 0; hc < 8; ++hc) {
      const float* src = qr + hc * 32 + g * 8;
      half8 h, l;
#pragma unroll
      for (int j = 0; j < 8; ++j) {
        float x = src[j];
        f16 hi = (f16)x;
        h[j] = hi;
        l[j] = (f16)(x - (float)hi);
      }
      qhi[hc] = h; qlo[hc] = l;
    }
  }

  floatx4 o[16];
#pragma unroll
  for (int t = 0; t < 16; ++t) o[t] = (floatx4){0.f, 0.f, 0.f, 0.f};
  float m_run = -INFINITY, l_run = 0.f;

  const f16* gKhi = Khi + tb * HDIM;
  const f16* gKlo = Klo + tb * HDIM;
  const f16* gVt  = Vt + (size_t)b * HDIM * TDIM;

  uint4 rkh[4], rkl[4], rv[4];
#pragma unroll
  for (int s = 0; s < 4; ++s) {              // prefetch tile 0
    int flat = tid + 256 * s;
    int kr = flat >> 5, kc = flat & 31;
    rkh[s] = *(const uint4*)(gKhi + (size_t)kr * HDIM + kc * 8);
    rkl[s] = *(const uint4*)(gKlo + (size_t)kr * HDIM + kc * 8);
    int vh = flat >> 2, vc = flat & 3;
    rv[s] = *(const uint4*)(gVt + (size_t)vh * TDIM + vc * 8);
  }

  for (int it = 0; it < TDIM / 32; ++it) {
    __syncthreads();
#pragma unroll
    for (int s = 0; s < 4; ++s) {            // write staged regs -> LDS
      int flat = tid + 256 * s;
      int kr = flat >> 5, kc = flat & 31;
      *(uint4*)(sKhi + kr * KPITCH + kc * 8) = rkh[s];
      *(uint4*)(sKlo + kr * KPITCH + kc * 8) = rkl[s];
      int vh = flat >> 2, vc = flat & 3;
      *(uint4*)(sVt + vh * VPITCH + vc * 8) = rv[s];
    }
    __syncthreads();
    if (it + 1 < TDIM / 32) {                // issue next tile loads (hide under compute)
      const int kb = (it + 1) * 32;
#pragma unroll
      for (int s = 0; s < 4; ++s) {
        int flat = tid + 256 * s;
        int kr = flat >> 5, kc = flat & 31;
        rkh[s] = *(const uint4*)(gKhi + (size_t)(kb + kr) * HDIM + kc * 8);
        rkl[s] = *(const uint4*)(gKlo + (size_t)(kb + kr) * HDIM + kc * 8);
        int vh = flat >> 2, vc = flat & 3;
        rv[s] = *(const uint4*)(gVt + (size_t)vh * TDIM + kb + vc * 8);
      }
    }

    // ---- S^T = K (hi/lo) x Q (hi/lo), 3-pass fp16x3, two 16-key tiles ----
    floatx4 st0 = {0.f, 0.f, 0.f, 0.f}, st1 = {0.f, 0.f, 0.f, 0.f};
#pragma unroll
    for (int hc = 0; hc < 8; ++hc) {
      U4 a0h, a0l, a1h, a1l;
      a0h.u = *(const uint4*)(sKhi + (0 + ql) * KPITCH + hc * 32 + g * 8);
      a0l.u = *(const uint4*)(sKlo + (0 + ql) * KPITCH + hc * 32 + g * 8);
      a1h.u = *(const uint4*)(sKhi + (16 + ql) * KPITCH + hc * 32 + g * 8);
      a1l.u = *(const uint4*)(sKlo + (16 + ql) * KPITCH + hc * 32 + g * 8);
      st0 = __builtin_amdgcn_mfma_f32_16x16x32_f16(a0h.h, qhi[hc], st0, 0, 0, 0);
      st1 = __builtin_amdgcn_mfma_f32_16x16x32_f16(a1h.h, qhi[hc], st1, 0, 0, 0);
      st0 = __builtin_amdgcn_mfma_f32_16x16x32_f16(a0h.h, qlo[hc], st0, 0, 0, 0);
      st1 = __builtin_amdgcn_mfma_f32_16x16x32_f16(a1h.h, qlo[hc], st1, 0, 0, 0);
      st0 = __builtin_amdgcn_mfma_f32_16x16x32_f16(a0l.h, qhi[hc], st0, 0, 0, 0);
      st1 = __builtin_amdgcn_mfma_f32_16x16x32_f16(a1l.h, qhi[hc], st1, 0, 0, 0);
    }

    // ---- online softmax (per-lane state for q = ql, replicated over g) ----
    float mx = fmaxf(fmaxf(fmaxf(st0[0], st0[1]), fmaxf(st0[2], st0[3])),
                     fmaxf(fmaxf(st1[0], st1[1]), fmaxf(st1[2], st1[3])));
    mx = fmaxf(mx, __shfl_xor(mx, 16, 64));
    mx = fmaxf(mx, __shfl_xor(mx, 32, 64));
    float alpha = 1.f;
    if (__any(mx > m_run)) {
      float mnew = fmaxf(m_run, mx);
      alpha = __expf(m_run - mnew);
      m_run = mnew;
      float a0 = __shfl(alpha, 4 * g + 0, 64);
      float a1 = __shfl(alpha, 4 * g + 1, 64);
      float a2 = __shfl(alpha, 4 * g + 2, 64);
      float a3 = __shfl(alpha, 4 * g + 3, 64);
#pragma unroll
      for (int t = 0; t < 16; ++t) {
        o[t][0] *= a0; o[t][1] *= a1; o[t][2] *= a2; o[t][3] *= a3;
      }
    }
    float pv0 = __expf(st0[0] - m_run), pv1 = __expf(st0[1] - m_run);
    float pv2 = __expf(st0[2] - m_run), pv3 = __expf(st0[3] - m_run);
    float pv4 = __expf(st1[0] - m_run), pv5 = __expf(st1[1] - m_run);
    float pv6 = __expf(st1[2] - m_run), pv7 = __expf(st1[3] - m_run);
    float sum = ((pv0 + pv1) + (pv2 + pv3)) + ((pv4 + pv5) + (pv6 + pv7));
    sum += __shfl_xor(sum, 16, 64);
    sum += __shfl_xor(sum, 32, 64);
    l_run = l_run * alpha + sum;

    // ---- P -> A-fragment (keys 8g..8g+7 per lane) via in-wave shuffles ----
    unsigned P0 = pk16(pv0, pv1), P1 = pk16(pv2, pv3);
    unsigned P2 = pk16(pv4, pv5), P3 = pk16(pv6, pv7);
    const int sA = ql + ((g & 1) << 5);
    const int sB = sA + 16;
    unsigned s0A = __shfl(P0, sA, 64), s2A = __shfl(P2, sA, 64);
    unsigned s1A = __shfl(P1, sA, 64), s3A = __shfl(P3, sA, 64);
    unsigned s0B = __shfl(P0, sB, 64), s2B = __shfl(P2, sB, 64);
    unsigned s1B = __shfl(P1, sB, 64), s3B = __shfl(P3, sB, 64);
    U4 paU;
    paU.u.x = (g < 2) ? s0A : s2A;
    paU.u.y = (g < 2) ? s1A : s3A;
    paU.u.z = (g < 2) ? s0B : s2B;
    paU.u.w = (g < 2) ? s1B : s3B;

    // ---- O += P @ V (K=32 keys in one MFMA per 16-h tile) ----
#pragma unroll
    for (int t = 0; t < 16; ++t) {
      U4 vb;
      vb.u = *(const uint4*)(sVt + (t * 16 + ql) * VPITCH + g * 8);
      o[t] = __builtin_amdgcn_mfma_f32_16x16x32_f16(paU.h, vb.h, o[t], 0, 0, 0);
    }
  }

  // ---- epilogue: normalize rows (4g+r) and store ----
  float r0 = 1.f / __shfl(l_run, 4 * g + 0, 64);
  float r1 = 1.f / __shfl(l_run, 4 * g + 1, 64);
  float r2 = 1.f / __shfl(l_run, 4 * g + 2, 64);
  float r3 = 1.f / __shfl(l_run, 4 * g + 3, 64);
#pragma unroll
  for (int t = 0; t < 16; ++t) {
    O[(tb + q0 + 4 * g + 0) * HDIM + t * 16 + ql] = o[t][0] * r0;
    O[(tb + q0 + 4 * g + 1) * HDIM + t * 16 + ql] = o[t][1] * r1;
    O[(tb + q0 + 4 * g + 2) * HDIM + t * 16 + ql] = o[t][2] * r2;
    O[(tb + q0 + 4 * g + 3) * HDIM + t * 16 + ql] = o[t][3] * r3;
  }
}

extern "C" void kernel_launch(void* const* d_in, const int* in_sizes, int n_in,
                              void* d_out, int out_size, void* d_ws, size_t ws_size,
                              hipStream_t stream) {
  const float* inp = (const float*)d_in[0];
  const float* Wq  = (const float*)d_in[1];
  const float* Wk  = (const float*)d_in[2];
  const float* Wv  = (const float*)d_in[3];
  float* out = (float*)d_out;

  // ws: Qs fp32 16.78MB | Khi f16 8.39MB | Klo f16 8.39MB | Vt f16 8.39MB = 41.9MB
  float* Qs = (float*)d_ws;
  f16* KhiP = (f16*)((char*)d_ws + (size_t)16384 * 256 * 4);
  f16* KloP = KhiP + (size_t)16384 * 256;
  f16* VtP  = KloP + (size_t)16384 * 256;

  qkv_gemm<<<dim3(16384 / 64, 12), 256, 0, stream>>>(inp, Wq, Wk, Wv, Qs, KhiP, KloP, VtP);
  attn_mfma<<<dim3(256), 256, 0, stream>>>(Qs, KhiP, KloP, VtP, out);
}

// Round 8
// 928.573 us; speedup vs baseline: 1.6777x; 1.0290x over previous
//
#include <hip/hip_runtime.h>
#include <hip/hip_fp16.h>
#include <math.h>

#define TDIM 4096
#define DDIM 1024
#define HDIM 256
#define BB   4
#define NROWS (BB * TDIM)          // 16384
#define NIT   64                   // key tiles per half (2048 / 32)

typedef _Float16 f16;
typedef f16  half8  __attribute__((ext_vector_type(8)));
typedef float floatx4 __attribute__((ext_vector_type(4)));

union U4 { uint4 u; half8 h; };
union U2 { uint2 u; f16 h[4]; };

#define KPITCH 264   // f16 per K_lds row (256 + 8 pad)
#define VPITCH 40    // f16 per V^T_lds row (32 + 8 pad)

__device__ inline unsigned pk16(float a, float b) {
  auto r = __builtin_amdgcn_cvt_pkrtz(a, b);
  return __builtin_bit_cast(unsigned, r);
}

// ---------------- Kernel 1: fused QKV projection (fp32 math) ----------------
__global__ __launch_bounds__(256) void qkv_gemm(
    const float* __restrict__ A,
    const float* __restrict__ Wq, const float* __restrict__ Wk, const float* __restrict__ Wv,
    float* __restrict__ Qs, f16* __restrict__ Khi, f16* __restrict__ Klo,
    f16* __restrict__ Vt)
{
  __shared__ float sAt[16][68];
  __shared__ float sB[16][68];
  __shared__ f16 sT[64][72];       // V-tile transpose buffer
  const int tid = threadIdx.x;
  const int tx = tid & 15, ty = tid >> 4;
  const int m0 = blockIdx.x * 64;
  const int nt = blockIdx.y;            // 0..11
  const int w  = nt >> 2;
  const int n0 = (nt & 3) * 64;
  const float* W = (w == 0) ? Wq : (w == 1) ? Wk : Wv;

  const int ar = tid >> 2, ac = (tid & 3) * 4;
  const int br = tid >> 4, bc = (tid & 15) * 4;

  float acc[4][4] = {};
  for (int k0 = 0; k0 < DDIM; k0 += 16) {
    float4 av = *reinterpret_cast<const float4*>(&A[(size_t)(m0 + ar) * DDIM + k0 + ac]);
    float4 bv = *reinterpret_cast<const float4*>(&W[(size_t)(k0 + br) * HDIM + n0 + bc]);
    __syncthreads();
    sAt[ac + 0][ar] = av.x; sAt[ac + 1][ar] = av.y;
    sAt[ac + 2][ar] = av.z; sAt[ac + 3][ar] = av.w;
    *reinterpret_cast<float4*>(&sB[br][bc]) = bv;
    __syncthreads();
#pragma unroll
    for (int kk = 0; kk < 16; ++kk) {
      float4 a4 = *reinterpret_cast<const float4*>(&sAt[kk][4 * ty]);
      float4 b4 = *reinterpret_cast<const float4*>(&sB[kk][4 * tx]);
      float a_[4] = {a4.x, a4.y, a4.z, a4.w};
      float b_[4] = {b4.x, b4.y, b4.z, b4.w};
#pragma unroll
      for (int i = 0; i < 4; ++i)
#pragma unroll
        for (int j = 0; j < 4; ++j)
          acc[i][j] = fmaf(a_[i], b_[j], acc[i][j]);
    }
  }
  if (w == 0) {
#pragma unroll
    for (int i = 0; i < 4; ++i) {
      float4 o4 = {acc[i][0] * 0.5f, acc[i][1] * 0.5f, acc[i][2] * 0.5f, acc[i][3] * 0.5f};
      *reinterpret_cast<float4*>(&Qs[(size_t)(m0 + 4 * ty + i) * HDIM + n0 + 4 * tx]) = o4;
    }
  } else if (w == 1) {
#pragma unroll
    for (int i = 0; i < 4; ++i) {
      U2 hh, ll;
#pragma unroll
      for (int j = 0; j < 4; ++j) {
        float x = acc[i][j];
        f16 hi = (f16)x;
        hh.h[j] = hi;
        ll.h[j] = (f16)(x - (float)hi);
      }
      size_t off = (size_t)(m0 + 4 * ty + i) * HDIM + n0 + 4 * tx;
      *reinterpret_cast<uint2*>(&Khi[off]) = hh.u;
      *reinterpret_cast<uint2*>(&Klo[off]) = ll.u;
    }
  } else {
    // transpose V tile in LDS, then coalesced store to Vt[b][h][t]
#pragma unroll
    for (int i = 0; i < 4; ++i)
#pragma unroll
      for (int j = 0; j < 4; ++j)
        sT[4 * tx + j][4 * ty + i] = (f16)acc[i][j];
    __syncthreads();
    const int row = tid >> 2, seg = tid & 3;
    uint4 w0 = *reinterpret_cast<uint4*>(&sT[row][seg * 16]);
    uint4 w1 = *reinterpret_cast<uint4*>(&sT[row][seg * 16 + 8]);
    size_t gb = (size_t)(m0 >> 12) * HDIM * TDIM + (size_t)(n0 + row) * TDIM
              + (m0 & 4095) + seg * 16;
    *reinterpret_cast<uint4*>(&Vt[gb]) = w0;
    *reinterpret_cast<uint4*>(&Vt[gb + 8]) = w1;
  }
}

// ---------------- Kernel 2: MFMA flash attention, split-K x2 ----------------
// grid 512: sel=i&7 -> b=sel>>1, half=sel&1 (one (b,half) per XCD); p=i>>3.
// Block: 64 q rows (4 waves x 16), keys [half*2048, +2048), partial (o,m,l) out.
__global__ __launch_bounds__(256, 2) void attn_mfma(
    const float* __restrict__ Qs, const f16* __restrict__ Khi,
    const f16* __restrict__ Klo, const f16* __restrict__ Vt,
    float* __restrict__ Po, float* __restrict__ Pm, float* __restrict__ Pl)
{
  __shared__ f16 sKhi[32 * KPITCH];
  __shared__ f16 sKlo[32 * KPITCH];
  __shared__ f16 sVt[256 * VPITCH];

  const int tid = threadIdx.x;
  const int lane = tid & 63;
  const int wv = tid >> 6;
  const int ql = lane & 15;
  const int g  = lane >> 4;

  const int i = blockIdx.x;
  const int sel = i & 7;
  const int b = sel >> 1;
  const int half = sel & 1;
  const int p = i >> 3;
  const size_t tb = (size_t)b * TDIM;
  const int koff = half * 2048;
  const int q0 = p * 64 + wv * 16;

  // ---- hoist Q fragments: split scaled fp32 Q into hi/lo f16 ----
  half8 qhi[8], qlo[8];
  {
    const float* qr = Qs + (tb + q0 + ql) * HDIM;
#pragma unroll
    for (int hc = 0; hc < 8; ++hc) {
      const float* src = qr + hc * 32 + g * 8;
      float4 u0 = *reinterpret_cast<const float4*>(src);
      float4 u1 = *reinterpret_cast<const float4*>(src + 4);
      float xs[8] = {u0.x, u0.y, u0.z, u0.w, u1.x, u1.y, u1.z, u1.w};
      half8 h, l;
#pragma unroll
      for (int j = 0; j < 8; ++j) {
        f16 hi = (f16)xs[j];
        h[j] = hi;
        l[j] = (f16)(xs[j] - (float)hi);
      }
      qhi[hc] = h; qlo[hc] = l;
    }
  }

  floatx4 o[16];
#pragma unroll
  for (int t = 0; t < 16; ++t) o[t] = (floatx4){0.f, 0.f, 0.f, 0.f};
  float m_run = -INFINITY, l_run = 0.f;

  const f16* gKhi = Khi + tb * HDIM;
  const f16* gKlo = Klo + tb * HDIM;
  const f16* gVt  = Vt + (size_t)b * HDIM * TDIM;

  uint4 rkh[4], rkl[4], rv[4];
#pragma unroll
  for (int s = 0; s < 4; ++s) {              // prefetch tile 0
    int flat = tid + 256 * s;
    int kr = flat >> 5, kc = flat & 31;
    rkh[s] = *(const uint4*)(gKhi + (size_t)(koff + kr) * HDIM + kc * 8);
    rkl[s] = *(const uint4*)(gKlo + (size_t)(koff + kr) * HDIM + kc * 8);
    int vh = flat >> 2, vc = flat & 3;
    rv[s] = *(const uint4*)(gVt + (size_t)vh * TDIM + koff + vc * 8);
  }

  for (int it = 0; it < NIT; ++it) {
    __syncthreads();
#pragma unroll
    for (int s = 0; s < 4; ++s) {            // staged regs -> LDS
      int flat = tid + 256 * s;
      int kr = flat >> 5, kc = flat & 31;
      *(uint4*)(sKhi + kr * KPITCH + kc * 8) = rkh[s];
      *(uint4*)(sKlo + kr * KPITCH + kc * 8) = rkl[s];
      int vh = flat >> 2, vc = flat & 3;
      *(uint4*)(sVt + vh * VPITCH + vc * 8) = rv[s];
    }
    __syncthreads();
    if (it + 1 < NIT) {                      // issue next-tile loads
      const int kb = koff + (it + 1) * 32;
#pragma unroll
      for (int s = 0; s < 4; ++s) {
        int flat = tid + 256 * s;
        int kr = flat >> 5, kc = flat & 31;
        rkh[s] = *(const uint4*)(gKhi + (size_t)(kb + kr) * HDIM + kc * 8);
        rkl[s] = *(const uint4*)(gKlo + (size_t)(kb + kr) * HDIM + kc * 8);
        int vh = flat >> 2, vc = flat & 3;
        rv[s] = *(const uint4*)(gVt + (size_t)vh * TDIM + kb + vc * 8);
      }
    }

    // ---- S^T via fp16x3, 6 independent accumulator chains ----
    floatx4 c0 = {0,0,0,0}, c1 = {0,0,0,0}, c2 = {0,0,0,0};
    floatx4 c3 = {0,0,0,0}, c4 = {0,0,0,0}, c5 = {0,0,0,0};
#pragma unroll
    for (int hc = 0; hc < 8; ++hc) {
      U4 a0h, a0l, a1h, a1l;
      a0h.u = *(const uint4*)(sKhi + (0 + ql) * KPITCH + hc * 32 + g * 8);
      a0l.u = *(const uint4*)(sKlo + (0 + ql) * KPITCH + hc * 32 + g * 8);
      a1h.u = *(const uint4*)(sKhi + (16 + ql) * KPITCH + hc * 32 + g * 8);
      a1l.u = *(const uint4*)(sKlo + (16 + ql) * KPITCH + hc * 32 + g * 8);
      c0 = __builtin_amdgcn_mfma_f32_16x16x32_f16(a0h.h, qhi[hc], c0, 0, 0, 0);
      c3 = __builtin_amdgcn_mfma_f32_16x16x32_f16(a1h.h, qhi[hc], c3, 0, 0, 0);
      c1 = __builtin_amdgcn_mfma_f32_16x16x32_f16(a0h.h, qlo[hc], c1, 0, 0, 0);
      c4 = __builtin_amdgcn_mfma_f32_16x16x32_f16(a1h.h, qlo[hc], c4, 0, 0, 0);
      c2 = __builtin_amdgcn_mfma_f32_16x16x32_f16(a0l.h, qhi[hc], c2, 0, 0, 0);
      c5 = __builtin_amdgcn_mfma_f32_16x16x32_f16(a1l.h, qhi[hc], c5, 0, 0, 0);
    }
    floatx4 st0 = (c0 + c1) + c2;
    floatx4 st1 = (c3 + c4) + c5;

    // ---- online softmax (state per q=ql, replicated over g), defer-max ----
    float mx = fmaxf(fmaxf(fmaxf(st0[0], st0[1]), fmaxf(st0[2], st0[3])),
                     fmaxf(fmaxf(st1[0], st1[1]), fmaxf(st1[2], st1[3])));
    mx = fmaxf(mx, __shfl_xor(mx, 16, 64));
    mx = fmaxf(mx, __shfl_xor(mx, 32, 64));
    float alpha = 1.f;
    if (__any(mx > m_run + 8.f)) {
      float mnew = fmaxf(m_run, mx);
      alpha = __expf(m_run - mnew);
      m_run = mnew;
      float a0 = __shfl(alpha, 4 * g + 0, 64);
      float a1 = __shfl(alpha, 4 * g + 1, 64);
      float a2 = __shfl(alpha, 4 * g + 2, 64);
      float a3 = __shfl(alpha, 4 * g + 3, 64);
#pragma unroll
      for (int t = 0; t < 16; ++t) {
        o[t][0] *= a0; o[t][1] *= a1; o[t][2] *= a2; o[t][3] *= a3;
      }
    }
    float pv0 = __expf(st0[0] - m_run), pv1 = __expf(st0[1] - m_run);
    float pv2 = __expf(st0[2] - m_run), pv3 = __expf(st0[3] - m_run);
    float pv4 = __expf(st1[0] - m_run), pv5 = __expf(st1[1] - m_run);
    float pv6 = __expf(st1[2] - m_run), pv7 = __expf(st1[3] - m_run);
    float sum = ((pv0 + pv1) + (pv2 + pv3)) + ((pv4 + pv5) + (pv6 + pv7));
    sum += __shfl_xor(sum, 16, 64);
    sum += __shfl_xor(sum, 32, 64);
    l_run = l_run * alpha + sum;

    // ---- P -> A-fragment (keys 8g..8g+7 per lane) ----
    unsigned P0 = pk16(pv0, pv1), P1 = pk16(pv2, pv3);
    unsigned P2 = pk16(pv4, pv5), P3 = pk16(pv6, pv7);
    const int sA = ql + ((g & 1) << 5);
    const int sB = sA + 16;
    unsigned s0A = __shfl(P0, sA, 64), s2A = __shfl(P2, sA, 64);
    unsigned s1A = __shfl(P1, sA, 64), s3A = __shfl(P3, sA, 64);
    unsigned s0B = __shfl(P0, sB, 64), s2B = __shfl(P2, sB, 64);
    unsigned s1B = __shfl(P1, sB, 64), s3B = __shfl(P3, sB, 64);
    U4 paU;
    paU.u.x = (g < 2) ? s0A : s2A;
    paU.u.y = (g < 2) ? s1A : s3A;
    paU.u.z = (g < 2) ? s0B : s2B;
    paU.u.w = (g < 2) ? s1B : s3B;

    // ---- O += P @ V ----
#pragma unroll
    for (int t = 0; t < 16; ++t) {
      U4 vb;
      vb.u = *(const uint4*)(sVt + (t * 16 + ql) * VPITCH + g * 8);
      o[t] = __builtin_amdgcn_mfma_f32_16x16x32_f16(paU.h, vb.h, o[t], 0, 0, 0);
    }
  }

  // ---- store partials (unnormalized) ----
  float* Pob = Po + (size_t)half * NROWS * HDIM;
#pragma unroll
  for (int t = 0; t < 16; ++t) {
    Pob[(tb + q0 + 4 * g + 0) * HDIM + t * 16 + ql] = o[t][0];
    Pob[(tb + q0 + 4 * g + 1) * HDIM + t * 16 + ql] = o[t][1];
    Pob[(tb + q0 + 4 * g + 2) * HDIM + t * 16 + ql] = o[t][2];
    Pob[(tb + q0 + 4 * g + 3) * HDIM + t * 16 + ql] = o[t][3];
  }
  if (g == 0) {
    Pm[(size_t)half * NROWS + tb + q0 + ql] = m_run;
    Pl[(size_t)half * NROWS + tb + q0 + ql] = l_run;
  }
}

// ---------------- Kernel 3: split-K merge ----------------
__global__ __launch_bounds__(256) void attn_merge(
    const float* __restrict__ Po, const float* __restrict__ Pm,
    const float* __restrict__ Pl, float* __restrict__ O)
{
  const int NV4 = NROWS * HDIM / 4;        // 1048576 float4
  const float4* Po4 = (const float4*)Po;
  float4* O4 = (float4*)O;
  for (int e = blockIdx.x * 256 + threadIdx.x; e < NV4; e += 2048 * 256) {
    int r = e >> 6;
    float m0 = Pm[r], m1 = Pm[NROWS + r];
    float l0 = Pl[r], l1 = Pl[NROWS + r];
    float M = fmaxf(m0, m1);
    float w0 = __expf(m0 - M), w1 = __expf(m1 - M);
    float L = 1.f / (l0 * w0 + l1 * w1);
    float4 a = Po4[e], c = Po4[NV4 + e];
    float4 r4 = {(a.x * w0 + c.x * w1) * L, (a.y * w0 + c.y * w1) * L,
                 (a.z * w0 + c.z * w1) * L, (a.w * w0 + c.w * w1) * L};
    O4[e] = r4;
  }
}

extern "C" void kernel_launch(void* const* d_in, const int* in_sizes, int n_in,
                              void* d_out, int out_size, void* d_ws, size_t ws_size,
                              hipStream_t stream) {
  const float* inp = (const float*)d_in[0];
  const float* Wq  = (const float*)d_in[1];
  const float* Wk  = (const float*)d_in[2];
  const float* Wv  = (const float*)d_in[3];
  float* out = (float*)d_out;

  // ws: Qs 16.78M | Khi 8.39M | Klo 8.39M | Vt 8.39M | Po 33.55M | Pm 128K | Pl 128K
  char* wp = (char*)d_ws;
  float* Qs = (float*)wp;                      wp += (size_t)NROWS * HDIM * 4;
  f16* KhiP = (f16*)wp;                        wp += (size_t)NROWS * HDIM * 2;
  f16* KloP = (f16*)wp;                        wp += (size_t)NROWS * HDIM * 2;
  f16* VtP  = (f16*)wp;                        wp += (size_t)NROWS * HDIM * 2;
  float* Po = (float*)wp;                      wp += (size_t)2 * NROWS * HDIM * 4;
  float* Pm = (float*)wp;                      wp += (size_t)2 * NROWS * 4;
  float* Pl = (float*)wp;

  qkv_gemm<<<dim3(NROWS / 64, 12), 256, 0, stream>>>(inp, Wq, Wk, Wv, Qs, KhiP, KloP, VtP);
  attn_mfma<<<dim3(512), 256, 0, stream>>>(Qs, KhiP, KloP, VtP, Po, Pm, Pl);
  attn_merge<<<dim3(2048), 256, 0, stream>>>(Po, Pm, Pl, out);
}